// Round 2
// baseline (1306.872 us; speedup 1.0000x reference)
//
#include <hip/hip_runtime.h>
#include <cstdint>

// ODE Euler scan: B=1024, T=4096, S=8, E=8, H=32.
// One wave per batch element; 1024 blocks x 64 threads = 1 wave/SIMD.
// Round-2 layout: lane l owns hidden units a=g and b=g+16 (g=l&15); every lane
// tracks the full 8-vector y redundantly (4 identical 16-lane groups).
// H-reduction = 4-stage pure-DPP butterfly within 16 lanes (no DS on the chain).

#if __has_builtin(__builtin_amdgcn_exp2f)
#define EXP2F(v) __builtin_amdgcn_exp2f(v)
#else
#define EXP2F(v) __exp2f(v)
#endif
#if __has_builtin(__builtin_amdgcn_rcpf)
#define RCPF(v) __builtin_amdgcn_rcpf(v)
#else
#define RCPF(v) (1.0f / (v))
#endif

typedef float v2f __attribute__((ext_vector_type(2)));

__device__ __forceinline__ v2f v2fma(v2f a, v2f b, v2f c) {
  return __builtin_elementwise_fma(a, b, c);
}
__device__ __forceinline__ v2f splat2(float x) {
  v2f r; r.x = x; r.y = x; return r;
}

template <int CTRL>
__device__ __forceinline__ float dpp_add(float x) {
  // old=0, bound_ctrl=1 -> fusable into v_add_f32_dpp (all ctrls are in-row).
  int sh = __builtin_amdgcn_update_dpp(0, __float_as_int(x), CTRL, 0xF, 0xF, true);
  return x + __int_as_float(sh);
}

// Sum over each 16-lane group; result valid in ALL lanes of the group.
__device__ __forceinline__ float reduce16_all(float x) {
  x = dpp_add<0xB1>(x);   // quad_perm [1,0,3,2]  : lane ^ 1
  x = dpp_add<0x4E>(x);   // quad_perm [2,3,0,1]  : lane ^ 2
  x = dpp_add<0x141>(x);  // row_half_mirror      : pairs quads within 8
  x = dpp_add<0x140>(x);  // row_mirror           : pairs halves within 16
  return x;
}

__global__ __launch_bounds__(64, 1) void ode_scan_kernel(
    const float* __restrict__ x, const float* __restrict__ t,
    const float* __restrict__ y0, const float* __restrict__ Wr1,
    const float* __restrict__ br1, const float* __restrict__ Wr2,
    const float* __restrict__ br2, const float* __restrict__ W1,
    const float* __restrict__ b1, const float* __restrict__ W2,
    const float* __restrict__ b2, float* __restrict__ out) {
  constexpr int T = 4096;

  __shared__ __align__(16) float t_lds[4096];      // t, then dt in-place
  __shared__ __align__(16) float xbuf[2 * 64 * 8]; // double-buffered x chunks
  __shared__ __align__(16) float ybuf[64 * 12];    // 64 y-slots, rows padded to 12
  __shared__ float hw[112];                        // W1(80) b1(10) W2(20) b2(2)

  const int l = threadIdx.x;
  const int b = blockIdx.x;
  const int g = l & 15;   // position within 16-group
  const int a = g;        // first owned hidden unit
  const int bu = g + 16;  // second owned hidden unit

  // ---- stage t into LDS (coalesced float4) ----
  const float4* t4 = (const float4*)t;
  #pragma unroll
  for (int it = 0; it < 16; ++it) {
    float4 v = t4[it * 64 + l];
    *(float4*)&t_lds[(it * 64 + l) * 4] = v;
  }
  // dt in place (single wave => DS in-order; reads of iter k precede iter k+1 writes)
  for (int it = 0; it < 64; ++it) {
    int i = it * 64 + l;
    float aa = t_lds[i];
    float cc = (i < T - 1) ? t_lds[i + 1] : 0.0f;
    t_lds[i] = cc - aa;  // slot 4095 garbage; never consumed
  }

  // ---- head weights into LDS ----
  for (int v = l; v < 112; v += 64) {
    float w;
    if (v < 80) w = W1[v];
    else if (v < 90) w = b1[v - 80];
    else if (v < 110) w = W2[v - 90];
    else w = b2[v - 110];
    hw[v] = w;
  }

  // ---- per-lane recurrence weights (pairs for units a,b) ----
  v2f wy2[8], we2[8];
  float w2a[8], w2b[8], br2s[8];
  #pragma unroll
  for (int s = 0; s < 8; ++s) {
    wy2[s].x = Wr1[s * 32 + a];
    wy2[s].y = Wr1[s * 32 + bu];
    we2[s].x = Wr1[(8 + s) * 32 + a];
    we2[s].y = Wr1[(8 + s) * 32 + bu];
    w2a[s] = Wr2[a * 8 + s];
    w2b[s] = Wr2[bu * 8 + s];
    br2s[s] = (g == 0) ? br2[s] : 0.0f;  // one lane per 16-group carries br2
  }
  v2f br1v; br1v.x = br1[a]; br1v.y = br1[bu];

  // ---- full y state per lane ----
  float y[8];
  #pragma unroll
  for (int s = 0; s < 8; ++s) y[s] = y0[b * 8 + s];

  // ---- stage x chunk 0 ----
  const float* xbase = x + (size_t)b * (T * 8);
  {
    float4 a0 = *(const float4*)&xbase[l * 8 + 0];
    float4 a1 = *(const float4*)&xbase[l * 8 + 4];
    *(float4*)&xbuf[l * 8 + 0] = a0;
    *(float4*)&xbuf[l * 8 + 4] = a1;
  }

  // record y0 into slot 0
  if (l == 0) {
    *(float4*)&ybuf[0] = make_float4(y[0], y[1], y[2], y[3]);
    *(float4*)&ybuf[4] = make_float4(y[4], y[5], y[6], y[7]);
  }

  float2* out2 = (float2*)out + (size_t)b * T;

  // prefetched e/dt for step 0
  float4 e0 = *(float4*)&xbuf[0];
  float4 e1 = *(float4*)&xbuf[4];
  float dtc = t_lds[0];

  #pragma unroll 1
  for (int c = 0; c < 64; ++c) {
    float4 g0 = make_float4(0.f, 0.f, 0.f, 0.f), g1 = g0;
    if (c < 63) {
      g0 = *(const float4*)&xbase[(c + 1) * 512 + l * 8 + 0];
      g1 = *(const float4*)&xbase[(c + 1) * 512 + l * 8 + 4];
    }

    auto step = [&](int k) {
      const int inext = c * 64 + k;  // current step index i = inext-1
      float4 ne0 = *(float4*)&xbuf[(inext & 127) * 8 + 0];
      float4 ne1 = *(float4*)&xbuf[(inext & 127) * 8 + 4];
      float ndt = t_lds[inext];

      // z = br1 + y·Wr1y + e·Wr1e  (pair over units a,b; split 4-deep chains)
      v2f ze1 = v2fma(splat2(e0.x), we2[0], br1v);
      ze1 = v2fma(splat2(e0.y), we2[1], ze1);
      ze1 = v2fma(splat2(e0.z), we2[2], ze1);
      ze1 = v2fma(splat2(e0.w), we2[3], ze1);
      v2f ze2 = splat2(e1.x) * we2[4];
      ze2 = v2fma(splat2(e1.y), we2[5], ze2);
      ze2 = v2fma(splat2(e1.z), we2[6], ze2);
      ze2 = v2fma(splat2(e1.w), we2[7], ze2);
      v2f zy1 = splat2(y[0]) * wy2[0];
      zy1 = v2fma(splat2(y[1]), wy2[1], zy1);
      zy1 = v2fma(splat2(y[2]), wy2[2], zy1);
      zy1 = v2fma(splat2(y[3]), wy2[3], zy1);
      v2f zy2 = splat2(y[4]) * wy2[4];
      zy2 = v2fma(splat2(y[5]), wy2[5], zy2);
      zy2 = v2fma(splat2(y[6]), wy2[6], zy2);
      zy2 = v2fma(splat2(y[7]), wy2[7], zy2);
      v2f z = (ze1 + ze2) + (zy1 + zy2);

      // tanh for both units: tanh(v) = 1 - 2/(exp2(2v*log2e)+1)
      float ua = EXP2F(z.x * 2.885390081777927f);
      float ub = EXP2F(z.y * 2.885390081777927f);
      float ha = fmaf(-2.0f, RCPF(ua + 1.0f), 1.0f);
      float hb = fmaf(-2.0f, RCPF(ub + 1.0f), 1.0f);

      // partials p_s = ha*W2[a][s] + hb*W2[b][s] (+br2 on lane g==0)
      float p[8];
      #pragma unroll
      for (int s = 0; s < 8; ++s)
        p[s] = fmaf(ha, w2a[s], fmaf(hb, w2b[s], br2s[s]));

      // 16-lane all-lanes butterfly => full 32-unit sums in every lane
      #pragma unroll
      for (int s = 0; s < 8; ++s) p[s] = reduce16_all(p[s]);

      // Euler update (all lanes hold full y)
      #pragma unroll
      for (int s = 0; s < 8; ++s) y[s] = fmaf(dtc, p[s], y[s]);

      // record y_{tau} (tau = inext) into slot k — lane 0 only, off-chain
      if (l == 0) {
        *(float4*)&ybuf[k * 12 + 0] = make_float4(y[0], y[1], y[2], y[3]);
        *(float4*)&ybuf[k * 12 + 4] = make_float4(y[4], y[5], y[6], y[7]);
      }

      e0 = ne0; e1 = ne1; dtc = ndt;
    };

    #pragma unroll 2
    for (int k = (c ? 0 : 1); k < 8; ++k) step(k);

    if (c < 63) {
      *(float4*)&xbuf[((c + 1) & 1) * 512 + l * 8 + 0] = g0;
      *(float4*)&xbuf[((c + 1) & 1) * 512 + l * 8 + 4] = g1;
    }

    #pragma unroll 2
    for (int k = 8; k < 64; ++k) step(k);

    // ---- head burst: lane l handles tau = c*64 + l ----
    {
      float4 ya = *(float4*)&ybuf[l * 12 + 0];
      float4 yb = *(float4*)&ybuf[l * 12 + 4];
      float ys[8] = {ya.x, ya.y, ya.z, ya.w, yb.x, yb.y, yb.z, yb.w};
      float o0 = hw[110], o1 = hw[111];
      #pragma unroll
      for (int m = 0; m < 10; ++m) {
        float hh = hw[80 + m];
        #pragma unroll
        for (int s = 0; s < 8; ++s) hh = fmaf(ys[s], hw[s * 10 + m], hh);
        hh = fmaxf(hh, 0.0f);
        o0 = fmaf(hh, hw[90 + m * 2 + 0], o0);
        o1 = fmaf(hh, hw[90 + m * 2 + 1], o1);
      }
      out2[c * 64 + l] = make_float2(o0, o1);
    }
  }
}

extern "C" void kernel_launch(void* const* d_in, const int* in_sizes, int n_in,
                              void* d_out, int out_size, void* d_ws, size_t ws_size,
                              hipStream_t stream) {
  const float* x   = (const float*)d_in[0];
  const float* t   = (const float*)d_in[1];
  const float* y0  = (const float*)d_in[2];
  const float* Wr1 = (const float*)d_in[3];
  const float* br1 = (const float*)d_in[4];
  const float* Wr2 = (const float*)d_in[5];
  const float* br2 = (const float*)d_in[6];
  const float* W1  = (const float*)d_in[7];
  const float* b1  = (const float*)d_in[8];
  const float* W2  = (const float*)d_in[9];
  const float* b2  = (const float*)d_in[10];
  (void)in_sizes; (void)n_in; (void)out_size; (void)d_ws; (void)ws_size;

  ode_scan_kernel<<<dim3(1024), dim3(64), 0, stream>>>(x, t, y0, Wr1, br1, Wr2,
                                                       br2, W1, b1, W2, b2,
                                                       (float*)d_out);
}